// Round 4
// baseline (1942.485 us; speedup 1.0000x reference)
//
#include <hip/hip_runtime.h>

// Problem constants (fixed by the reference)
constexpr int BB = 32;     // batch
constexpr int DD = 384;    // latent dim
constexpr int TN = 4096;   // sequence length
constexpr int KK = 256;    // codebook size
constexpr float BETA = 0.25f;

constexpr int TT  = 64;           // tokens per block
constexpr int DG  = DD / 4;       // 96 float4 groups along D
constexpr int ECH = 4;            // dg-groups per LDS chunk
constexpr int NCH = DG / ECH;     // 24 chunks

constexpr size_t QSIZE = (size_t)BB * DD * TN;   // 50331648
constexpr size_t ISIZE = (size_t)BB * TN;        // 131072

// async global->LDS, 16B per lane; LDS dest = wave-uniform base + lane*16
__device__ __forceinline__ void gl_lds16(const float4* g, float4* l) {
    __builtin_amdgcn_global_load_lds(
        (const __attribute__((address_space(1))) void*)g,
        (__attribute__((address_space(3))) void*)l, 16, 0, 0);
}

// --- pre-pass: per-code squared norms (parallel; also zeroes the loss slot,
// replacing the memset dispatch — d_out is poisoned 0xAA before every call) ---
__global__ void e2_kernel(const float* __restrict__ cb, float* __restrict__ e2,
                          float* __restrict__ loss_slot) {
    const int c = blockIdx.x;        // KK blocks
    const int l = threadIdx.x;       // 64 lanes
    const float4* row = (const float4*)(cb + (size_t)c * DD);
    float4 v = row[l];
    float s = v.x * v.x + v.y * v.y + v.z * v.z + v.w * v.w;
    if (l < DG - 64) {               // lanes 0..31 take the second group
        float4 w = row[64 + l];
        s += w.x * w.x + w.y * w.y + w.z * w.z + w.w * w.w;
    }
    #pragma unroll
    for (int m = 32; m >= 1; m >>= 1) s += __shfl_xor(s, m, 64);
    if (l == 0) e2[c] = s;
    if (c == 0 && l == 0) *loss_slot = 0.f;
}

// --- main fused kernel: distances + argmin + quantize + indices + loss ---
// 8 tokens x 8 codes per thread (R3-verified balance). R4 change: LDS double
// buffer + one barrier per chunk. Chunk ch: issue z loads + global_load_lds
// for ch+1 into buf nxt, compute ch from buf cur (~2000 FMA cyc hides the
// ~900 cyc load latency), ds_write z, barrier (compiler's vmcnt(0) drain
// lands AFTER compute, not before it as in R3).
// R2 lessons kept: no es4 padding (contiguous b128 is conflict-free); no
// bulk prefetch regs (spill); launch_bounds(256,2) for a 256-reg budget.
__global__ __launch_bounds__(256, 2)
void vq_kernel(const float* __restrict__ z, const float* __restrict__ cb,
               const float* __restrict__ e2g, float* __restrict__ out) {
    __shared__ float4 es4[2][ECH][KK];   // 32 KB codebook chunks, [buf][dgl][code]
    __shared__ float4 xs4[2][ECH][TT];   //  8 KB z chunks, [buf][dgl][token]
    __shared__ float  e2s[KK];           //  1 KB
    __shared__ int    idxs[TT];
    __shared__ float  wsum[4];

    const int tid = threadIdx.x;
    const int bid = blockIdx.x;
    const int b   = bid >> 6;                 // TN/TT = 64 tiles per batch
    const int t0  = (bid & 63) * TT;

    const int tx = tid & 31;                  // -> codes  c = tx + 32*j
    const int ty = tid >> 5;                  // -> tokens t = ty*8 + i
    const int wb = tid & ~63;                 // wave-uniform lane base

    e2s[tid] = e2g[tid];

    const float*  zb  = z + (size_t)b * DD * TN + t0;
    const float4* cb4 = (const float4*)cb;

    const int xr  = tid >> 6;      // z staging: dgl row (0..3)
    const int xtt = tid & 63;      // z staging: token (coalesced)

    // prologue: stage chunk 0 into buf 0
    {
        #pragma unroll
        for (int dgl = 0; dgl < ECH; ++dgl)
            gl_lds16(&cb4[(size_t)tid * DG + dgl], &es4[0][dgl][wb]);
        float x0 = zb[(size_t)(4 * xr + 0) * TN + xtt];
        float x1 = zb[(size_t)(4 * xr + 1) * TN + xtt];
        float x2 = zb[(size_t)(4 * xr + 2) * TN + xtt];
        float x3 = zb[(size_t)(4 * xr + 3) * TN + xtt];
        xs4[0][xr][xtt] = make_float4(x0, x1, x2, x3);
    }
    __syncthreads();

    float acc[8][8];
    #pragma unroll
    for (int i = 0; i < 8; ++i)
        #pragma unroll
        for (int j = 0; j < 8; ++j) acc[i][j] = 0.f;

    for (int ch = 0; ch < NCH; ++ch) {
        const int cur = ch & 1, nxt = cur ^ 1;
        const bool pf = (ch + 1 < NCH);
        float x0, x1, x2, x3;
        if (pf) {   // issue next chunk's loads first; they land during compute
            const int dgb = (ch + 1) * ECH;
            x0 = zb[(size_t)(4 * (dgb + xr) + 0) * TN + xtt];
            x1 = zb[(size_t)(4 * (dgb + xr) + 1) * TN + xtt];
            x2 = zb[(size_t)(4 * (dgb + xr) + 2) * TN + xtt];
            x3 = zb[(size_t)(4 * (dgb + xr) + 3) * TN + xtt];
            #pragma unroll
            for (int dgl = 0; dgl < ECH; ++dgl)
                gl_lds16(&cb4[(size_t)tid * DG + dgb + dgl], &es4[nxt][dgl][wb]);
        }

        #pragma unroll
        for (int dgl = 0; dgl < ECH; ++dgl) {
            float4 xv[8];
            #pragma unroll
            for (int i = 0; i < 8; ++i) xv[i] = xs4[cur][dgl][ty * 8 + i];  // broadcast
            #pragma unroll
            for (int j = 0; j < 8; ++j) {
                float4 ev = es4[cur][dgl][tx + 32 * j];                     // contiguous b128
                #pragma unroll
                for (int i = 0; i < 8; ++i) {
                    acc[i][j] += xv[i].x * ev.x;
                    acc[i][j] += xv[i].y * ev.y;
                    acc[i][j] += xv[i].z * ev.z;
                    acc[i][j] += xv[i].w * ev.w;
                }
            }
        }

        if (pf) xs4[nxt][xr][xtt] = make_float4(x0, x1, x2, x3);  // sunk after compute
        __syncthreads();   // single barrier/chunk: next buf fully staged
    }

    // per-thread argmin over its 8 codes (c ascending => first-min kept)
    float bv[8]; int bi[8];
    #pragma unroll
    for (int i = 0; i < 8; ++i) { bv[i] = 3.4e38f; bi[i] = 0x7fffffff; }
    #pragma unroll
    for (int j = 0; j < 8; ++j) {
        const int c = tx + 32 * j;
        const float e2c = e2s[c];
        #pragma unroll
        for (int i = 0; i < 8; ++i) {
            float v = e2c - 2.f * acc[i][j];    // x^2 constant per token: drop it
            if (v < bv[i]) { bv[i] = v; bi[i] = c; }
        }
    }
    // cross-lane reduce over the 32 tx lanes (lexicographic: val, then index)
    #pragma unroll
    for (int m = 16; m >= 1; m >>= 1) {
        #pragma unroll
        for (int i = 0; i < 8; ++i) {
            float ov = __shfl_xor(bv[i], m, 64);
            int   oi = __shfl_xor(bi[i], m, 64);
            if (ov < bv[i] || (ov == bv[i] && oi < bi[i])) { bv[i] = ov; bi[i] = oi; }
        }
    }
    if (tx == 0) {
        #pragma unroll
        for (int i = 0; i < 8; ++i) idxs[ty * 8 + i] = bi[i];
    }
    __syncthreads();

    // epilogue: quantize output (coalesced over t), loss partials
    {
        const int myi = idxs[xtt];
        const float4* crow = cb4 + (size_t)myi * DG;
        float* outq = out + (size_t)b * DD * TN + t0;
        float lsum = 0.f;
        #pragma unroll
        for (int m = 0; m < 24; ++m) {
            int dg = xr + 4 * m;
            float4 q = crow[dg];                               // L2-hot gather
            float x0 = zb[(size_t)(4 * dg + 0) * TN + xtt];    // coalesced re-read
            float x1 = zb[(size_t)(4 * dg + 1) * TN + xtt];
            float x2 = zb[(size_t)(4 * dg + 2) * TN + xtt];
            float x3 = zb[(size_t)(4 * dg + 3) * TN + xtt];
            float d0 = q.x - x0, d1 = q.y - x1, d2 = q.z - x2, d3 = q.w - x3;
            lsum += d0 * d0 + d1 * d1 + d2 * d2 + d3 * d3;
            outq[(size_t)(4 * dg + 0) * TN + xtt] = q.x;
            outq[(size_t)(4 * dg + 1) * TN + xtt] = q.y;
            outq[(size_t)(4 * dg + 2) * TN + xtt] = q.z;
            outq[(size_t)(4 * dg + 3) * TN + xtt] = q.w;
        }
        // indices output (as float: whole out buffer is fp32)
        if (tid < TT)
            out[QSIZE + (size_t)b * TN + t0 + tid] = (float)idxs[tid];

        // loss: wave reduce -> block reduce -> one atomic
        #pragma unroll
        for (int m = 32; m >= 1; m >>= 1) lsum += __shfl_xor(lsum, m, 64);
        if ((tid & 63) == 0) wsum[tid >> 6] = lsum;
        __syncthreads();
        if (tid == 0) {
            float s = wsum[0] + wsum[1] + wsum[2] + wsum[3];
            atomicAdd(out + QSIZE + ISIZE,
                      s * (BETA / (float)((size_t)BB * DD * TN)));
        }
    }
}

extern "C" void kernel_launch(void* const* d_in, const int* in_sizes, int n_in,
                              void* d_out, int out_size, void* d_ws, size_t ws_size,
                              hipStream_t stream) {
    (void)in_sizes; (void)n_in; (void)out_size; (void)ws_size;
    const float* z  = (const float*)d_in[0];
    const float* cb = (const float*)d_in[1];
    float* out  = (float*)d_out;
    float* e2ws = (float*)d_ws;

    e2_kernel<<<dim3(KK), dim3(64), 0, stream>>>(cb, e2ws, out + QSIZE + ISIZE);
    vq_kernel<<<dim3(BB * (TN / TT)), dim3(256), 0, stream>>>(z, cb, e2ws, out);
}